// Round 1
// baseline (1174.215 us; speedup 1.0000x reference)
//
#include <hip/hip_runtime.h>

// Problem constants (from reference): M=5, N=2 -> U=3, GROUPS=4, DIL=2,
// KSIZE=13, B=8, C=O=256, T=16384, Ti=8192, BOUNDARY=sqrt(2).
#define TI 8192
#define T_FULL 16384
#define TILE 32      // output positions per phase per block
#define EXT 36       // TILE + 4 (halo for denom 5-window)
#define PPQ 9        // extended positions per q-thread (4*9 = 36)
#define XS_STRIDE 41 // 40 xs values per (i,c) row + 1 pad
#define W_STRIDE 65  // 64 o + 1 pad
#define S0_STRIDE 37 // 36 + 1 pad
#define OUT_STRIDE 68 // 64 + 4 pad (keeps float4 alignment)
#define CCHUNK 8

#define XS_SIZE (2 * 64 * XS_STRIDE)      // 5248 floats
#define WL_SIZE (CCHUNK * 13 * W_STRIDE)  // 6760 floats
// s0l aliases xsl region (2*64*37 = 4736 <= 5248)
// outl aliases wl region (64*68 = 4352 <= 6760)

__global__ __launch_bounds__(256, 2)
void pconv_kernel(const float* __restrict__ x, const float* __restrict__ w,
                  const float* __restrict__ bias, float* __restrict__ out) {
    __shared__ float smem[XS_SIZE + WL_SIZE];  // 48032 B
    float* xsl  = smem;            // [i][c][m_rel], m_rel in [0,40)
    float* wl   = smem + XS_SIZE;  // [cc*13+k][o]
    float* s0l  = smem;            // alias: [i][o][pe], pe in [0,36)
    float* outl = smem + XS_SIZE;  // alias: [o][u], u in [0,64)

    const int tile    = blockIdx.x;   // 0..255
    const int g       = blockIdx.y;   // 0..3
    const int bb      = blockIdx.z;   // 0..7
    const int t_start = tile * TILE;

    const int tid = threadIdx.x;
    const int o   = tid >> 2;  // 0..63 output channel within group
    const int q   = tid & 3;   // 0..3  t-subtile

    // ---- stage x tile (both phases, contiguous global read, de-interleave) ----
    // need xs[c, m] for m in [t_start-4, t_start+35]  ->  x[b, c, v], v = 2m+i
    const float* xb = x + ((size_t)(bb * 256 + g * 64)) * T_FULL;
    const int v0 = 2 * t_start - 8;
    for (int f = tid; f < 64 * 80; f += 256) {
        int c  = f / 80;
        int vv = f - c * 80;
        int v  = v0 + vv;
        float val = 0.0f;
        if (v >= 0 && v < T_FULL) val = xb[(size_t)c * T_FULL + v];
        xsl[(vv & 1) * (64 * XS_STRIDE) + c * XS_STRIDE + (vv >> 1)] = val;
    }

    // accumulators: s0 (W0 taps), s_d2 (W1 taps), s_d1 (W2 taps)
    float acc0[2][PPQ], acc1[2][PPQ], acc2[2][PPQ];
    #pragma unroll
    for (int i = 0; i < 2; i++)
        #pragma unroll
        for (int p = 0; p < PPQ; p++) { acc0[i][p] = 0.f; acc1[i][p] = 0.f; acc2[i][p] = 0.f; }

    const float* wg = w + (size_t)(g * 64) * 832;  // this group's weights (64 o x 64 c x 13)

    for (int c0 = 0; c0 < 64; c0 += CCHUNK) {
        __syncthreads();  // protect wl reuse (first iter: xsl visibility)
        // stage weight chunk: wl[(cc*13+k)][o] <- w[g*64+o][c0+cc][k]
        for (int f = tid; f < CCHUNK * 13 * 64; f += 256) {
            int ow = f / (CCHUNK * 13);
            int r  = f - ow * (CCHUNK * 13);  // cc*13 + k, contiguous in global
            wl[r * W_STRIDE + ow] = wg[(size_t)ow * 832 + c0 * 13 + r];
        }
        __syncthreads();

        for (int cc = 0; cc < CCHUNK; cc++) {
            float wreg[13];
            #pragma unroll
            for (int k = 0; k < 13; k++) wreg[k] = wl[(cc * 13 + k) * W_STRIDE + o];
            #pragma unroll
            for (int i = 0; i < 2; i++) {
                const float* xc = xsl + i * (64 * XS_STRIDE) + (c0 + cc) * XS_STRIDE + q * PPQ;
                float xr[13];
                #pragma unroll
                for (int e = 0; e < 13; e++) xr[e] = xc[e];
                float dxr[12];
                #pragma unroll
                for (int e = 0; e < 12; e++) dxr[e] = xr[e + 1] - xr[e];
                #pragma unroll
                for (int p = 0; p < PPQ; p++) {
                    float a0 = acc0[i][p], a1 = acc1[i][p], a2 = acc2[i][p];
                    #pragma unroll
                    for (int j = 0; j < 4; j++) {
                        a0 = fmaf(wreg[3 * j],     xr[p + j],  a0);
                        a1 = fmaf(wreg[3 * j + 1], dxr[p + j], a1);  // d2
                        a2 = fmaf(wreg[3 * j + 2], dxr[p + j], a2);  // d1
                    }
                    acc0[i][p] = fmaf(wreg[12], xr[p + 4], a0);
                    acc1[i][p] = a1;
                    acc2[i][p] = a2;
                }
            }
        }
    }

    const float bv = bias[g * 64 + o];

    __syncthreads();  // all xsl/wl reads done -> safe to overwrite via aliases

    // ---- write masked t0 (= s0 + bias, zero outside [2, Ti-3]) into LDS ----
    #pragma unroll
    for (int i = 0; i < 2; i++) {
        #pragma unroll
        for (int p = 0; p < PPQ; p++) {
            int pe = q * PPQ + p;         // 0..35 extended index
            int tg = t_start - 2 + pe;    // global position
            float v = ((tg >= 2) && (tg <= TI - 3)) ? (acc0[i][p] + bv) : 0.0f;
            s0l[i * (64 * S0_STRIDE) + o * S0_STRIDE + pe] = v;
        }
    }
    __syncthreads();

    // ---- denom + combine, write interleaved tile to LDS ----
    #pragma unroll
    for (int i = 0; i < 2; i++) {
        const float* s0row = s0l + i * (64 * S0_STRIDE) + o * S0_STRIDE;
        #pragma unroll
        for (int p = 0; p < PPQ; p++) {
            int pe = q * PPQ + p;
            if (pe >= 2 && pe < 34) {
                int j  = pe - 2;           // 0..31 output index within tile
                int tg = t_start + j;
                bool valid = (tg >= 2) && (tg <= TI - 3);
                float t0v = s0row[pe];
                float m5  = 0.2f * (s0row[pe - 2] + s0row[pe - 1] + t0v +
                                    s0row[pe + 1] + s0row[pe + 2]);
                float dv  = t0v - m5;
                float den = fminf(fmaxf(dv, 1.0f), 1.41421356237309515f);
                float r   = 1.0f / den;
                float d1  = valid ? acc2[i][p] : 0.0f;  // W2-conv of dx
                float d2  = valid ? acc1[i][p] : 0.0f;  // W1-conv of dx
                float res = 0.25f * (t0v + (d1 + d2) * r + 2.0f * (d2 - d1) * r * r);
                outl[o * OUT_STRIDE + 2 * j + i] = res;
            }
        }
    }
    __syncthreads();

    // ---- coalesced float4 store: 64 rows x 64 contiguous floats ----
    float* ob = out + ((size_t)(bb * 256 + g * 64)) * T_FULL + 2 * t_start;
    #pragma unroll
    for (int k = 0; k < 4; k++) {
        int row = k * 16 + (tid >> 4);
        int u4  = (tid & 15) * 4;
        const float4 vv = *(const float4*)(outl + row * OUT_STRIDE + u4);
        *(float4*)(ob + (size_t)row * T_FULL + u4) = vv;
    }
}

extern "C" void kernel_launch(void* const* d_in, const int* in_sizes, int n_in,
                              void* d_out, int out_size, void* d_ws, size_t ws_size,
                              hipStream_t stream) {
    const float* x = (const float*)d_in[0];   // (8, 256, 16384) f32
    const float* w = (const float*)d_in[1];   // (256, 64, 13)   f32
    const float* b = (const float*)d_in[2];   // (256,)          f32
    float* out = (float*)d_out;               // (8, 256, 16384) f32

    dim3 grid(TI / TILE, 4, 8);  // 256 t-tiles x 4 groups x 8 batch
    pconv_kernel<<<grid, 256, 0, stream>>>(x, w, b, out);
}

// Round 2
// 424.359 us; speedup vs baseline: 2.7670x; 2.7670x over previous
//
#include <hip/hip_runtime.h>

// Constants: M=5,N=2 -> U=3, GROUPS=4, DIL=2, KSIZE=13; B=8, C=O=256, T=16384,
// Ti=8192, BOUNDARY=sqrt(2). Folded form: t0/d2/d1 are each 5-tap convs over
// xs_i[c,m]=x[b,c,2m+i]:
//   t0[t] = mask * (sum_e w0[e]*xs[t-2+e] + bias)        w0[e]=w[.,.,3e]
//   d2[t] = mask * sum_e (w1[e-1]-w1[e])*xs[t-2+e]       w1[j]=w[.,.,3j+1]
//   d1[t] = mask * sum_e (w2[e-1]-w2[e])*xs[t-2+e]       w2[j]=w[.,.,3j+2]
//   den   = clip(t0 - mean5(t0), 1, sqrt(2))
//   out[2t+i] = 0.25*(t0 + (d1+d2)/den + 2*(d2-d1)/den^2),  mask: 2<=t<=8189

typedef float v4f __attribute__((ext_vector_type(4)));
typedef short v8s __attribute__((ext_vector_type(8)));

#define TI 8192
#define TFULL 16384
#define TB 128              // stored outputs per phase per block
#define XPH_BYTES 18944     // 148 rows * 128 B (swizzled [t][c] bf16 tile)
#define T0L_F 0             // f32 index of t0l  [144][68]
#define D2L_F 9792          // 144*68
#define D1L_F 19584
#define BIAS_F 29376        // 64 floats
#define LDS_BYTES 117760    // 29376*4 + 256

__device__ __forceinline__ unsigned bf16w(float f) {
    unsigned u = __float_as_uint(f);
    return (u + 0x7FFFu + ((u >> 16) & 1u)) >> 16;
}

// ---------------- prep: fold weights into bf16 A-fragments ----------------
// ws element layout (ushort): ((((g*5+e)*2+kc)*12+mt)*64+lane)*8+j
// holds A[m][k]: m=16*mt+(lane&15) (row: a=m>>6 acc, o=16*(mt&3)+(lane&15)),
// k=32*kc+(lane>>4)*8+j = channel c.
__global__ void prep_kernel(const float* __restrict__ w, unsigned short* __restrict__ gw) {
    int id = blockIdx.x * 256 + threadIdx.x;   // 245760 total
    int j    = id & 7;
    int lane = (id >> 3) & 63;
    int fid  = id >> 9;
    int mt   = fid % 12;  fid /= 12;
    int kc   = fid & 1;   fid >>= 1;
    int e    = fid % 5;
    int g    = fid / 5;
    int a  = mt >> 2;
    int mg = mt & 3;
    int o  = 16 * mg + (lane & 15);
    int c  = 32 * kc + (lane >> 4) * 8 + j;
    const float* wb = w + (((size_t)(g * 64 + o)) * 64 + c) * 13;
    float val;
    if (a == 0) {
        val = wb[3 * e];
    } else {
        int tap = (a == 1) ? 1 : 2;
        float lo = (e > 0) ? wb[3 * (e - 1) + tap] : 0.0f;
        float hi = (e < 4) ? wb[3 * e + tap] : 0.0f;
        val = lo - hi;
    }
    gw[id] = (unsigned short)bf16w(val);
}

// ---------------- main ----------------
__global__ __launch_bounds__(512, 2)
void pconv_mfma(const unsigned short* __restrict__ gw, const float* __restrict__ x,
                const float* __restrict__ bias, float* __restrict__ out) {
    extern __shared__ char smem[];
    float* smemf = (float*)smem;

    const int tid  = threadIdx.x;
    const int lane = tid & 63;
    const int wv   = tid >> 6;      // 0..7
    const int mg   = wv >> 1;       // o-slice [16mg,16mg+16)
    const int ph   = wv & 1;        // dilation phase
    const int col  = lane & 15;
    const int quad = lane >> 4;

    const int tileIdx = blockIdx.x;       // 0..63
    const int g       = blockIdx.y;       // 0..3
    const int b       = blockIdx.z;       // 0..7
    const int tb      = tileIdx * TB;

    // ---- stage bias ----
    if (tid < 64) smemf[BIAS_F + tid] = bias[g * 64 + tid];

    // ---- stage x: de-interleave + transpose + bf16, XOR-swizzled [t][c] ----
    // phase tile p: rows trel in [0,148) <-> m = tb-4+trel; 16B block of 8 ch at
    // byte: p*XPH + trel*128 + ((cblk ^ (trel&7))<<4) + (c&7)*2
    {
        const float* xb = x + ((size_t)(b * 256 + g * 64)) * TFULL;
        const int v0 = 2 * tb - 8;          // 296 values per channel
        for (int f = tid; f < 2368; f += 512) {       // 32 cpairs * 74 vquads
            int q  = f % 74;
            int cp = f / 74;
            int vq = v0 + 4 * q;
            const float* r0 = xb + (size_t)(2 * cp) * TFULL;
            const float* r1 = r0 + TFULL;
            float a0, a1, a2, a3, b0, b1, b2, b3;
            if (vq >= 0 && vq + 3 < TFULL) {
                v4f A4 = *(const v4f*)(r0 + vq);
                v4f B4 = *(const v4f*)(r1 + vq);
                a0 = A4[0]; a1 = A4[1]; a2 = A4[2]; a3 = A4[3];
                b0 = B4[0]; b1 = B4[1]; b2 = B4[2]; b3 = B4[3];
            } else {
                a0 = (vq >= 0 && vq < TFULL) ? r0[vq] : 0.0f;
                a1 = (vq + 1 >= 0 && vq + 1 < TFULL) ? r0[vq + 1] : 0.0f;
                a2 = (vq + 2 >= 0 && vq + 2 < TFULL) ? r0[vq + 2] : 0.0f;
                a3 = (vq + 3 >= 0 && vq + 3 < TFULL) ? r0[vq + 3] : 0.0f;
                b0 = (vq >= 0 && vq < TFULL) ? r1[vq] : 0.0f;
                b1 = (vq + 1 >= 0 && vq + 1 < TFULL) ? r1[vq + 1] : 0.0f;
                b2 = (vq + 2 >= 0 && vq + 2 < TFULL) ? r1[vq + 2] : 0.0f;
                b3 = (vq + 3 >= 0 && vq + 3 < TFULL) ? r1[vq + 3] : 0.0f;
            }
            int cblk = cp >> 2;
            int woff = (cp & 3) * 4;
            unsigned w0 = bf16w(a0) | (bf16w(b0) << 16);  // p=0, trel=2q
            unsigned w1 = bf16w(a1) | (bf16w(b1) << 16);  // p=1, trel=2q
            unsigned w2 = bf16w(a2) | (bf16w(b2) << 16);  // p=0, trel=2q+1
            unsigned w3 = bf16w(a3) | (bf16w(b3) << 16);  // p=1, trel=2q+1
            int t0r = 2 * q, t1r = 2 * q + 1;
            *(unsigned*)(smem + 0 * XPH_BYTES + t0r * 128 + ((cblk ^ (t0r & 7)) << 4) + woff) = w0;
            *(unsigned*)(smem + 1 * XPH_BYTES + t0r * 128 + ((cblk ^ (t0r & 7)) << 4) + woff) = w1;
            *(unsigned*)(smem + 0 * XPH_BYTES + t1r * 128 + ((cblk ^ (t1r & 7)) << 4) + woff) = w2;
            *(unsigned*)(smem + 1 * XPH_BYTES + t1r * 128 + ((cblk ^ (t1r & 7)) << 4) + woff) = w3;
        }
    }
    __syncthreads();

    // ---- K-loop: 10 ksteps (5 taps x 2 kchunks), 27 MFMAs each ----
    const unsigned short* gwp = gw + (size_t)g * 61440;
    v4f acc[3][9];
    #pragma unroll
    for (int a = 0; a < 3; ++a)
        #pragma unroll
        for (int u = 0; u < 9; ++u) acc[a][u] = (v4f){0.f, 0.f, 0.f, 0.f};

    const char* xph = smem + ph * XPH_BYTES;
    #pragma unroll
    for (int e = 0; e < 5; ++e) {
        #pragma unroll
        for (int kc = 0; kc < 2; ++kc) {
            v8s Af[3];
            #pragma unroll
            for (int a = 0; a < 3; ++a)
                Af[a] = *(const v8s*)(gwp + (((e * 2 + kc) * 12 + 4 * a + mg) << 9) + (lane << 3));
            // B addr: xrel = 16u+col+e; block-swizzle sel = (col+e)&7
            const int sw = (col + e) * 128 + (((4 * kc + quad) ^ ((col + e) & 7)) << 4);
            #pragma unroll
            for (int u = 0; u < 9; ++u) {
                v8s Bf = *(const v8s*)(xph + u * 2048 + sw);
                #pragma unroll
                for (int a = 0; a < 3; ++a)
                    acc[a][u] = __builtin_amdgcn_mfma_f32_16x16x32_bf16(Af[a], Bf, acc[a][u], 0, 0, 0);
            }
        }
    }
    __syncthreads();   // GEMM done; safe to alias x tile with epilogue buffers

    // ---- epilogue, phase-serial ----
    const int o0 = 16 * mg + 4 * quad;                 // C/D row base for this lane
    const v4f bias4 = *(const v4f*)(smemf + BIAS_F + o0);
    const size_t outbase = ((size_t)(b * 256 + g * 64)) * TFULL;

    #pragma unroll
    for (int p = 0; p < 2; ++p) {
        if (ph == p) {
            // stage t0/d2/d1 to [idx][o] (stride 68), masked (+bias for t0)
            #pragma unroll
            for (int a = 0; a < 3; ++a) {
                float* dst = smemf + (a == 0 ? T0L_F : (a == 1 ? D2L_F : D1L_F));
                #pragma unroll
                for (int u = 0; u < 9; ++u) {
                    int idx = 16 * u + col;            // t = tb-2+idx
                    int t = tb - 2 + idx;
                    bool valid = (t >= 2) && (t <= TI - 3);
                    v4f v = acc[a][u];
                    if (a == 0) v = v + bias4;
                    if (!valid) v = (v4f){0.f, 0.f, 0.f, 0.f};
                    *(v4f*)(dst + idx * 68 + o0) = v;
                }
            }
        }
        __syncthreads();
        // combine: 2048 (o, j-quad) items, lanes o-major (conflict-free reads)
        #pragma unroll
        for (int it = 0; it < 4; ++it) {
            int f = tid + it * 512;
            int o = f & 63;
            int jq = f >> 6;                            // 0..31
            int j0 = 4 * jq;
            float r[8];
            #pragma unroll
            for (int c = 0; c < 8; ++c) r[c] = smemf[T0L_F + (j0 + c) * 68 + o];
            float d2v[4], d1v[4];
            #pragma unroll
            for (int s = 0; s < 4; ++s) {
                d2v[s] = smemf[D2L_F + (j0 + s + 2) * 68 + o];
                d1v[s] = smemf[D1L_F + (j0 + s + 2) * 68 + o];
            }
            float* ob = out + outbase + (size_t)o * TFULL;
            #pragma unroll
            for (int s = 0; s < 4; ++s) {
                float t0 = r[s + 2];
                float m5 = 0.2f * (r[s] + r[s + 1] + r[s + 2] + r[s + 3] + r[s + 4]);
                float den = fminf(fmaxf(t0 - m5, 1.0f), 1.41421356237309515f);
                float rc = 1.0f / den;
                float res = 0.25f * (t0 + (d1v[s] + d2v[s]) * rc +
                                     2.0f * (d2v[s] - d1v[s]) * rc * rc);
                ob[2 * (tb + j0 + s) + p] = res;
            }
        }
        __syncthreads();
    }
}

extern "C" void kernel_launch(void* const* d_in, const int* in_sizes, int n_in,
                              void* d_out, int out_size, void* d_ws, size_t ws_size,
                              hipStream_t stream) {
    const float* x  = (const float*)d_in[0];  // (8, 256, 16384) f32
    const float* w  = (const float*)d_in[1];  // (256, 64, 13)   f32
    const float* bb = (const float*)d_in[2];  // (256,)          f32
    float* out = (float*)d_out;

    unsigned short* gw = (unsigned short*)d_ws;   // 245760 ushort = 491520 B

    prep_kernel<<<960, 256, 0, stream>>>(w, gw);
    pconv_mfma<<<dim3(64, 4, 8), 512, LDS_BYTES, stream>>>(gw, x, bb, out);
}